// Round 1
// baseline (4946.431 us; speedup 1.0000x reference)
//
#include <hip/hip_runtime.h>
#include <stdint.h>

#define TN 1024
#define CD 192
#define NB 8
#define NCLUST 196

typedef unsigned long long ull;

__device__ __forceinline__ uint32_t f2sort(float f) {
    uint32_t u = __float_as_uint(f);
    return u ^ ((u >> 31) ? 0xFFFFFFFFu : 0x80000000u);
}

__device__ __forceinline__ ull wave_min_ull(ull v) {
    #pragma unroll
    for (int off = 32; off > 0; off >>= 1) {
        ull o = (ull)__shfl_xor((long long)v, off, 64);
        if (o < v) v = o;
    }
    return v;
}

// ---------------- normalize rows: xn = x / ||x|| ----------------
__global__ void norm_kernel(const float* __restrict__ x, float* __restrict__ xn) {
    int row = blockIdx.x;          // 0..NB*TN-1
    int t = threadIdx.x;           // 256 threads, 192 active
    __shared__ float ssum[4];
    float v = 0.f;
    if (t < CD) v = x[(size_t)row * CD + t];
    float s = v * v;
    #pragma unroll
    for (int off = 32; off > 0; off >>= 1) s += __shfl_xor(s, off, 64);
    if ((t & 63) == 0) ssum[t >> 6] = s;
    __syncthreads();
    float tot = ssum[0] + ssum[1] + ssum[2] + ssum[3];
    float nrm = __fsqrt_rn(tot);
    if (t < CD) xn[(size_t)row * CD + t] = __fdiv_rn(v, nrm);
}

// ---------------- dist = 1 - xn @ xn^T, 64x64 tiles ----------------
#define KC 32
__global__ __launch_bounds__(256) void dist_kernel(const float* __restrict__ xn,
                                                   float* __restrict__ dout,
                                                   float* __restrict__ dwork) {
    int b = blockIdx.z;
    int bm = blockIdx.y, bn = blockIdx.x;
    const float* X = xn + (size_t)b * TN * CD;
    __shared__ float As[KC][68];
    __shared__ float Bs[KC][68];
    int tid = threadIdx.x;
    int tx = tid & 15, ty = tid >> 4;
    int lr = tid >> 2;   // 0..63 (row within tile)
    int lq = tid & 3;    // float4 slot
    float acc[4][4];
    #pragma unroll
    for (int r = 0; r < 4; ++r)
        #pragma unroll
        for (int c = 0; c < 4; ++c) acc[r][c] = 0.f;

    for (int kc = 0; kc < CD; kc += KC) {
        float4 a0 = *(const float4*)&X[(size_t)(bm * 64 + lr) * CD + kc + lq * 4];
        float4 a1 = *(const float4*)&X[(size_t)(bm * 64 + lr) * CD + kc + (lq + 4) * 4];
        float4 b0 = *(const float4*)&X[(size_t)(bn * 64 + lr) * CD + kc + lq * 4];
        float4 b1 = *(const float4*)&X[(size_t)(bn * 64 + lr) * CD + kc + (lq + 4) * 4];
        __syncthreads();
        As[lq * 4 + 0][lr] = a0.x; As[lq * 4 + 1][lr] = a0.y;
        As[lq * 4 + 2][lr] = a0.z; As[lq * 4 + 3][lr] = a0.w;
        As[lq * 4 + 16][lr] = a1.x; As[lq * 4 + 17][lr] = a1.y;
        As[lq * 4 + 18][lr] = a1.z; As[lq * 4 + 19][lr] = a1.w;
        Bs[lq * 4 + 0][lr] = b0.x; Bs[lq * 4 + 1][lr] = b0.y;
        Bs[lq * 4 + 2][lr] = b0.z; Bs[lq * 4 + 3][lr] = b0.w;
        Bs[lq * 4 + 16][lr] = b1.x; Bs[lq * 4 + 17][lr] = b1.y;
        Bs[lq * 4 + 18][lr] = b1.z; Bs[lq * 4 + 19][lr] = b1.w;
        __syncthreads();
        #pragma unroll
        for (int kk = 0; kk < KC; ++kk) {
            float4 av = *(const float4*)&As[kk][ty * 4];
            float4 bv = *(const float4*)&Bs[kk][tx * 4];
            acc[0][0] += av.x * bv.x; acc[0][1] += av.x * bv.y;
            acc[0][2] += av.x * bv.z; acc[0][3] += av.x * bv.w;
            acc[1][0] += av.y * bv.x; acc[1][1] += av.y * bv.y;
            acc[1][2] += av.y * bv.z; acc[1][3] += av.y * bv.w;
            acc[2][0] += av.z * bv.x; acc[2][1] += av.z * bv.y;
            acc[2][2] += av.z * bv.z; acc[2][3] += av.z * bv.w;
            acc[3][0] += av.w * bv.x; acc[3][1] += av.w * bv.y;
            acc[3][2] += av.w * bv.z; acc[3][3] += av.w * bv.w;
        }
    }
    size_t obase = (size_t)b * TN * TN;
    #pragma unroll
    for (int r = 0; r < 4; ++r) {
        int mrow = bm * 64 + ty * 4 + r;
        float4 o;
        o.x = 1.0f - acc[r][0]; o.y = 1.0f - acc[r][1];
        o.z = 1.0f - acc[r][2]; o.w = 1.0f - acc[r][3];
        size_t idx = obase + (size_t)mrow * TN + bn * 64 + tx * 4;
        *(float4*)&dout[idx] = o;
        *(float4*)&dwork[idx] = o;
    }
}

// ---------------- per-row argmin init ----------------
__global__ void rowmin_init_kernel(const float* __restrict__ D, ull* __restrict__ rowkey) {
    int gid = blockIdx.x;            // b*TN + r
    int bb = gid >> 10, r = gid & 1023;
    const float* Drow = D + (size_t)bb * TN * TN + (size_t)r * TN;
    int t = threadIdx.x;             // 256
    ull k = ~0ull;
    for (int s = t; s < TN; s += 256) {
        if (s != r) {
            ull key = ((ull)f2sort(Drow[s]) << 32) | (uint32_t)s;
            if (key < k) k = key;
        }
    }
    k = wave_min_ull(k);
    __shared__ ull part[4];
    if ((t & 63) == 0) part[t >> 6] = k;
    __syncthreads();
    if (t == 0) {
        ull m = part[0];
        #pragma unroll
        for (int w = 1; w < 4; ++w) if (part[w] < m) m = part[w];
        rowkey[gid] = m;
    }
}

// ---------------- sequential agglomerative clustering, 1 block per batch ----------------
__global__ __launch_bounds__(1024) void cluster_kernel(float* __restrict__ D,
                                                       const ull* __restrict__ rowkey_init,
                                                       float* __restrict__ out_labels) {
    int b = blockIdx.x;
    float* Db = D + (size_t)b * TN * TN;
    int k = threadIdx.x;
    int lane = k & 63, wave = k >> 6;

    __shared__ ull rowkey[TN];          // (sortable val << 32) | argmin col
    __shared__ float sizes_l[TN];
    __shared__ int labels_l[TN];
    __shared__ unsigned char active_l[TN];
    __shared__ int list_l[TN];
    __shared__ int nrec;
    __shared__ ull wpart[16];
    __shared__ int bc_i, bc_j;
    __shared__ int prefix_w[16];
    __shared__ int woff[16];

    rowkey[k] = rowkey_init[b * TN + k];
    sizes_l[k] = 1.0f;
    labels_l[k] = k;
    active_l[k] = 1;
    __syncthreads();

    for (int m = 0; m < TN - NCLUST; ++m) {
        // ---- Phase A: global argmin over (val, row) ----
        ull gk = active_l[k] ? ((rowkey[k] & 0xFFFFFFFF00000000ull) | (uint32_t)k) : ~0ull;
        gk = wave_min_ull(gk);
        if (lane == 0) wpart[wave] = gk;
        if (k == 0) nrec = 0;
        __syncthreads();
        if (k == 0) {
            ull mn = wpart[0];
            #pragma unroll
            for (int w = 1; w < 16; ++w) if (wpart[w] < mn) mn = wpart[w];
            int ii = (int)(uint32_t)mn;
            bc_i = ii;
            bc_j = (int)(uint32_t)rowkey[ii];
        }
        __syncthreads();
        int i = bc_i, j = bc_j;
        float ni = sizes_l[i], nj = sizes_l[j];

        // ---- Phase B: averaged row, symmetric write, incremental rowmin ----
        float di = Db[(size_t)i * TN + k];
        float dj = Db[(size_t)j * TN + k];
        float nr = __fdiv_rn(__fadd_rn(__fmul_rn(ni, di), __fmul_rn(nj, dj)),
                             __fadd_rn(ni, nj));
        Db[(size_t)i * TN + k] = nr;     // row i (coalesced)
        Db[(size_t)k * TN + i] = nr;     // col i (scattered)
        bool rec = false;
        if (k == i) {
            rec = true;                   // full recompute of merged row
        } else if (k != j && active_l[k]) {
            ull K = rowkey[k];
            uint32_t c = (uint32_t)K;
            uint32_t vhi = (uint32_t)(K >> 32);
            uint32_t nrs = f2sort(nr);
            if (c == (uint32_t)j) rec = true;
            else if (c == (uint32_t)i) {
                if (nrs > vhi) rec = true;
                else rowkey[k] = ((ull)nrs << 32) | (uint32_t)i;
            } else {
                ull cand = ((ull)nrs << 32) | (uint32_t)i;
                if (cand < K) rowkey[k] = cand;
            }
        }
        if (rec) { int idx = atomicAdd(&nrec, 1); list_l[idx] = k; }
        __syncthreads();   // D writes + rec list complete

        // ---- Phase B2: state updates ----
        if (k == 0) { active_l[j] = 0; sizes_l[i] = __fadd_rn(ni, nj); }
        if (labels_l[k] == j) labels_l[k] = i;
        int nr_cnt = nrec;
        __syncthreads();

        // ---- Phase C: recompute rows whose NN was invalidated (1 wave / row) ----
        for (int base = 0; base < nr_cnt; base += 16) {
            int idx = base + wave;
            if (idx < nr_cnt) {
                int r = list_l[idx];
                const float* Dr = Db + (size_t)r * TN;
                ull kmin = ~0ull;
                for (int s = lane; s < TN; s += 64) {
                    if (active_l[s] && s != r) {
                        ull key = ((ull)f2sort(Dr[s]) << 32) | (uint32_t)s;
                        if (key < kmin) kmin = key;
                    }
                }
                kmin = wave_min_ull(kmin);
                if (lane == 0) rowkey[r] = kmin;
            }
        }
        __syncthreads();
    }

    // ---- epilogue: labels -> rank of representative among sorted active reps ----
    int a = active_l[k] ? 1 : 0;
    ull mask = __ballot(a);
    int lanepre = __popcll(mask & (((ull)1 << lane) - 1ull));
    if (lane == 0) prefix_w[wave] = __popcll(mask);
    __syncthreads();
    if (k == 0) {
        int run = 0;
        for (int w = 0; w < 16; ++w) { woff[w] = run; run += prefix_w[w]; }
    }
    __syncthreads();
    list_l[k] = woff[wave] + lanepre;   // rank[k] = #active < k
    __syncthreads();
    out_labels[(size_t)b * TN + k] = (float)list_l[labels_l[k]];
}

extern "C" void kernel_launch(void* const* d_in, const int* in_sizes, int n_in,
                              void* d_out, int out_size, void* d_ws, size_t ws_size,
                              hipStream_t stream) {
    const float* x = (const float*)d_in[0];
    float* out = (float*)d_out;

    float* xn    = (float*)d_ws;                          // NB*TN*CD floats (6.3 MB)
    float* Dwork = xn + (size_t)NB * TN * CD;             // NB*TN*TN floats (33.6 MB)
    ull*   rowkey = (ull*)(Dwork + (size_t)NB * TN * TN); // NB*TN u64 (64 KB)

    float* dist_out   = out;
    float* labels_out = out + (size_t)NB * TN * TN;

    norm_kernel<<<NB * TN, 256, 0, stream>>>(x, xn);
    dim3 g2(16, 16, NB);
    dist_kernel<<<g2, 256, 0, stream>>>(xn, dist_out, Dwork);
    rowmin_init_kernel<<<NB * TN, 256, 0, stream>>>(Dwork, rowkey);
    cluster_kernel<<<NB, 1024, 0, stream>>>(Dwork, rowkey, labels_out);
}